// Round 6
// baseline (201.068 us; speedup 1.0000x reference)
//
#include <hip/hip_runtime.h>
#include <hip/hip_bf16.h>
#include <stdint.h>

// Problem constants
#define BATCH 8
#define CH    256     // C
#define CQK   32      // query/key channels
#define NPIX  4096    // H*W
#define MALL  320     // CQK + CQK + CH combined projection rows

using bfrag = __attribute__((ext_vector_type(8))) short;     // 8 bf16 = 4 VGPR (MFMA A/B)
using f32x4 = __attribute__((ext_vector_type(4))) float;     // MFMA C/D
using u32x2 = __attribute__((ext_vector_type(2))) unsigned int;

#define MFMA16(A, B, C) __builtin_amdgcn_mfma_f32_16x16x32_bf16(A, B, C, 0, 0, 0)

#if __has_builtin(__builtin_amdgcn_exp2f)
#define EXP2(x) __builtin_amdgcn_exp2f(x)
#else
#define EXP2(x) exp2f(x)
#endif

__device__ __forceinline__ unsigned short f2bf(float f) {
  union { float f; unsigned int u; } v; v.f = f;
  unsigned int r = v.u + 0x7FFFu + ((v.u >> 16) & 1u);   // RNE
  return (unsigned short)(r >> 16);
}

__device__ __forceinline__ unsigned pkbf(float a, float b) {
  unsigned r;
  asm("v_cvt_pk_bf16_f32 %0, %1, %2" : "=v"(r) : "v"(a), "v"(b));
  return r;
}

__device__ __forceinline__ void gload_lds16(const void* g, void* l) {
  __builtin_amdgcn_global_load_lds(
      (const __attribute__((address_space(1))) unsigned int*)g,
      (__attribute__((address_space(3))) unsigned int*)l, 16, 0, 0);
}

// ---------------- kernel 0: cast weights to bf16 ----------------
__global__ void prep_kernel(const float* __restrict__ Wf, const float* __restrict__ Wg,
                            const float* __restrict__ Wh, const float* __restrict__ Wv,
                            unsigned short* __restrict__ Wall, unsigned short* __restrict__ Wvb) {
  int i = blockIdx.x * 256 + threadIdx.x;
  if (i < MALL * CH) {
    int m = i >> 8, c = i & 255;
    float v = (m < CQK)     ? Wf[m * CH + c]
            : (m < 2 * CQK) ? Wg[(m - CQK) * CH + c]
                            : Wh[(m - 2 * CQK) * CH + c];
    Wall[i] = f2bf(v);
  }
  if (i < CH * CH) Wvb[i] = f2bf(Wv[i]);
}

// ---------------- kernel 1: f,g,h projections (MFMA GEMM) ----------------
// out[m][n] = sum_c Wall[m][c] * x[b][c][n]  for one 64-pixel tile; M=320, K=256.
// Q is pre-scaled by log2(e). V is written FRAGMENT-MAJOR with a j-bit
// permutation sigma inside each 64-pixel tile:
//   slot kappa holds global j with j4=k2, j3=k4, j2=k3 (bits 5,1,0 identity)
// so the attention kernel's PV A-operand (P values) is exactly each lane's own
// S output registers -- no LDS / shuffle P exchange needed.
__global__ __launch_bounds__(256, 2)
void proj_kernel(const float* __restrict__ x, const unsigned short* __restrict__ Wall,
                 const float* __restrict__ bfb, const float* __restrict__ bgb,
                 const float* __restrict__ bhb,
                 unsigned short* __restrict__ Qo, unsigned short* __restrict__ Ko,
                 unsigned short* __restrict__ Vp) {
  __shared__ char xT[64 * 512];  // xT[n][c] bf16, rows 512B, 16B-chunk XOR (n&7)
  const int b  = blockIdx.x & 7;
  const int n0 = (blockIdx.x >> 3) * 64;
  const int tid = threadIdx.x;
  const int lane = tid & 63, wave = tid >> 6;
  const int lr = lane & 15, g = lane >> 4;

  // load + transpose x tile (fp32 -> bf16)
  for (int it = 0; it < 16; ++it) {
    int c = it * 16 + wave * 4 + g;
    int nn = lr * 4;
    const float4 v = *(const float4*)(x + (size_t)(b * CH + c) * NPIX + n0 + nn);
    const float* vp = (const float*)&v;
#pragma unroll
    for (int j = 0; j < 4; ++j) {
      int n = nn + j;
      int byteoff = n * 512 + (((c >> 3) ^ (n & 7)) << 4) + ((c & 7) * 2);
      *(unsigned short*)(xT + byteoff) = f2bf(vp[j]);
    }
  }
  __syncthreads();

  f32x4 acc[5][4] = {};
  for (int ks = 0; ks < 8; ++ks) {
    bfrag bfr[4];
#pragma unroll
    for (int nt = 0; nt < 4; ++nt) {
      int n = nt * 16 + lr;
      bfr[nt] = *(const bfrag*)(xT + n * 512 + (((ks * 4 + g) ^ (n & 7)) << 4));
    }
#pragma unroll
    for (int i = 0; i < 5; ++i) {
      int m = (wave + 4 * i) * 16 + lr;
      bfrag afr = *(const bfrag*)(Wall + (size_t)m * CH + ks * 32 + g * 8);
#pragma unroll
      for (int nt = 0; nt < 4; ++nt) acc[i][nt] = MFMA16(afr, bfr[nt], acc[i][nt]);
    }
  }

  const float L2E = 1.4426950408889634f;
  const int vtile = (b * 64 + (n0 >> 6)) * 256;   // fragment-major V tile base
#pragma unroll
  for (int i = 0; i < 5; ++i) {
    const int mt = wave + 4 * i;
#pragma unroll
    for (int nt = 0; nt < 4; ++nt) {
      const int nl = nt * 16 + lr;        // n within tile
      const int n  = n0 + nl;
      if (mt < 2) {                     // f -> Q (scaled by log2 e)
        float v0 = (acc[i][nt][0] + bfb[mt * 16 + 4 * g + 0]) * L2E;
        float v1 = (acc[i][nt][1] + bfb[mt * 16 + 4 * g + 1]) * L2E;
        float v2 = (acc[i][nt][2] + bfb[mt * 16 + 4 * g + 2]) * L2E;
        float v3 = (acc[i][nt][3] + bfb[mt * 16 + 4 * g + 3]) * L2E;
        u32x2 pk;
        pk[0] = (unsigned)f2bf(v0) | ((unsigned)f2bf(v1) << 16);
        pk[1] = (unsigned)f2bf(v2) | ((unsigned)f2bf(v3) << 16);
        *(u32x2*)(Qo + (size_t)(b * NPIX + n) * CQK + mt * 16 + 4 * g) = pk;
      } else if (mt < 4) {              // g -> K
        int k0 = (mt - 2) * 16 + 4 * g;
        float v0 = acc[i][nt][0] + bgb[k0 + 0];
        float v1 = acc[i][nt][1] + bgb[k0 + 1];
        float v2 = acc[i][nt][2] + bgb[k0 + 2];
        float v3 = acc[i][nt][3] + bgb[k0 + 3];
        u32x2 pk;
        pk[0] = (unsigned)f2bf(v0) | ((unsigned)f2bf(v1) << 16);
        pk[1] = (unsigned)f2bf(v2) | ((unsigned)f2bf(v3) << 16);
        *(u32x2*)(Ko + (size_t)(b * NPIX + n) * CQK + k0) = pk;
      } else {                          // h -> V fragment-major, sigma-permuted
        // kappa = sigma^-1(nl): k2=nl4, k4=nl3, k3=nl2; bits 5,1,0 unchanged
        const int kap = (nl & 35) | ((nl & 16) >> 2) | ((nl & 12) << 1);
#pragma unroll
        for (int r = 0; r < 4; ++r) {
          int c = mt * 16 + 4 * g + r - 64;
          Vp[(size_t)(vtile + c) * 64 + kap] = f2bf(acc[i][nt][r] + bhb[c]);
        }
      }
    }
  }
}

// ---------------- kernel 2: flash attention, fully in-register P ----------
// 512 blocks (batch = bid&7 XCD-pinned, 64-q tile). 4 INDEPENDENT waves:
// each wave computes the full S tile (64j x 64q, 16 MFMA) and PV for its own
// 64-channel slice (32 MFMA). The sigma-permuted V layout makes each lane's
// PV A-operand equal its own exp(S) registers: ZERO LDS, ZERO barriers,
// ZERO cross-lane ops in the loop. Waves free-run; softmax normalization in
// the epilogue via 2 shfl_xor + shfl.
__global__ __launch_bounds__(256)
void attn_kernel(const unsigned short* __restrict__ Qg, const unsigned short* __restrict__ Kg,
                 const unsigned short* __restrict__ Vp, unsigned short* __restrict__ Og) {
  const int bid = blockIdx.x;
  const int b  = bid & 7;                   // batch == XCD pin
  const int q0 = (bid >> 3) * 64;
  const int lane = threadIdx.x & 63, wave = threadIdx.x >> 6;
  const int lr = lane & 15, g = lane >> 4;

  const unsigned short* Qbase = Qg + (size_t)(b * NPIX + q0) * CQK;
  const unsigned short* Kf    = Kg + (size_t)b * NPIX * CQK + lr * CQK + g * 8;
  const unsigned short* Vf    = Vp + ((size_t)b * 64 * CH + wave * 64 + lr) * 64 + g * 8;

  // persistent Q fragments (B-operand of S): Q[nt*16+lr][8g..8g+7]
  bfrag qf[4];
#pragma unroll
  for (int nt = 0; nt < 4; ++nt)
    qf[nt] = *(const bfrag*)(Qbase + (nt * 16 + lr) * CQK + g * 8);

  f32x4 acc[4][4] = {};                     // [q-tile mt][c-tile ct2]
  float lp[4] = {0.f, 0.f, 0.f, 0.f};

  union BF { bfrag v; unsigned u[4]; };

  // K fragments for tile 0
  bfrag kc[4];
#pragma unroll
  for (int jt = 0; jt < 4; ++jt)
    kc[jt] = *(const bfrag*)(Kf + (size_t)(jt * 16) * CQK);

#pragma unroll 2
  for (int t = 0; t < 64; ++t) {
    const unsigned short* vt = Vf + (size_t)t * CH * 64;
    // V fragments ks=0 for tile t (consumed after S phase)
    bfrag vfA[4];
#pragma unroll
    for (int ct2 = 0; ct2 < 4; ++ct2)
      vfA[ct2] = *(const bfrag*)(vt + ct2 * 16 * 64);
    // K fragments for tile t+1
    bfrag kn[4];
    const int tn = (t + 1) & 63;
#pragma unroll
    for (int jt = 0; jt < 4; ++jt)
      kn[jt] = *(const bfrag*)(Kf + (size_t)(tn * 64 + jt * 16) * CQK);

    // ---- S phase: full 64j x 64q, exp2, pack to PV A-fragments (in-reg)
    BF pf0[4], pf1[4];                      // per q-tile: ks=0 / ks=1 fragments
#pragma unroll
    for (int nt = 0; nt < 4; ++nt) {
      f32x4 z = {0.f, 0.f, 0.f, 0.f};
      f32x4 s0 = MFMA16(kc[0], qf[nt], z);
      f32x4 s1 = MFMA16(kc[1], qf[nt], z);
      f32x4 s2 = MFMA16(kc[2], qf[nt], z);
      f32x4 s3 = MFMA16(kc[3], qf[nt], z);
      float p00 = EXP2(s0[0]), p01 = EXP2(s0[1]), p02 = EXP2(s0[2]), p03 = EXP2(s0[3]);
      float p10 = EXP2(s1[0]), p11 = EXP2(s1[1]), p12 = EXP2(s1[2]), p13 = EXP2(s1[3]);
      float p20 = EXP2(s2[0]), p21 = EXP2(s2[1]), p22 = EXP2(s2[2]), p23 = EXP2(s2[3]);
      float p30 = EXP2(s3[0]), p31 = EXP2(s3[1]), p32 = EXP2(s3[2]), p33 = EXP2(s3[3]);
      lp[nt] += ((p00 + p01) + (p02 + p03)) + ((p10 + p11) + (p12 + p13))
              + ((p20 + p21) + (p22 + p23)) + ((p30 + p31) + (p32 + p33));
      pf0[nt].u[0] = pkbf(p00, p01); pf0[nt].u[1] = pkbf(p02, p03);
      pf0[nt].u[2] = pkbf(p10, p11); pf0[nt].u[3] = pkbf(p12, p13);
      pf1[nt].u[0] = pkbf(p20, p21); pf1[nt].u[1] = pkbf(p22, p23);
      pf1[nt].u[2] = pkbf(p30, p31); pf1[nt].u[3] = pkbf(p32, p33);
    }

    // V fragments ks=1 (latency covered by PV ks=0)
    bfrag vfB[4];
#pragma unroll
    for (int ct2 = 0; ct2 < 4; ++ct2)
      vfB[ct2] = *(const bfrag*)(vt + ct2 * 16 * 64 + 32);

    // ---- PV phase: wave's 64-c slice
#pragma unroll
    for (int mt = 0; mt < 4; ++mt)
#pragma unroll
      for (int ct2 = 0; ct2 < 4; ++ct2)
        acc[mt][ct2] = MFMA16(pf0[mt].v, vfA[ct2], acc[mt][ct2]);
#pragma unroll
    for (int mt = 0; mt < 4; ++mt)
#pragma unroll
      for (int ct2 = 0; ct2 < 4; ++ct2)
        acc[mt][ct2] = MFMA16(pf1[mt].v, vfB[ct2], acc[mt][ct2]);

#pragma unroll
    for (int jt = 0; jt < 4; ++jt) kc[jt] = kn[jt];
  }

  // ---- epilogue: row sums (within-wave), normalize, store
#pragma unroll
  for (int nt = 0; nt < 4; ++nt) {
    lp[nt] += __shfl_xor(lp[nt], 16);
    lp[nt] += __shfl_xor(lp[nt], 32);
  }
  float inv[4][4];
#pragma unroll
  for (int mt = 0; mt < 4; ++mt)
#pragma unroll
    for (int r = 0; r < 4; ++r)
      inv[mt][r] = 1.0f / __shfl(lp[mt], 4 * g + r);

#pragma unroll
  for (int mt = 0; mt < 4; ++mt)
#pragma unroll
    for (int ct2 = 0; ct2 < 4; ++ct2) {
      int c = wave * 64 + ct2 * 16 + lr;
#pragma unroll
      for (int r = 0; r < 4; ++r) {
        int q = q0 + mt * 16 + 4 * g + r;
        Og[(size_t)(b * NPIX + q) * CH + c] = f2bf(acc[mt][ct2][r] * inv[mt][r]);
      }
    }
}

// ---------------- kernel 3: v-projection + residual ----------------
// out[b][m][n] = x[b][m][n] + gamma * (sum_c Wv[m][c]*attH[b][n][c] + bv[m])
__global__ __launch_bounds__(256, 2)
void vproj_kernel(const unsigned short* __restrict__ attn, const unsigned short* __restrict__ Wvb,
                  const float* __restrict__ bv, const float* __restrict__ x,
                  const float* __restrict__ gamma, float* __restrict__ out) {
  __shared__ char at[64 * 512];   // attH tile [64 n][256 c] bf16, swizzled
  const int b  = blockIdx.x & 7;
  const int n0 = (blockIdx.x >> 3) * 64;
  const int tid = threadIdx.x;
  const int lane = tid & 63, wave = tid >> 6;
  const int lr = lane & 15, g = lane >> 4;

#pragma unroll
  for (int i = 0; i < 8; ++i) {
    int ch = i * 256 + tid;
    int n = ch >> 5, G = ch & 31;
    gload_lds16(attn + (size_t)(b * NPIX + n0 + n) * CH + (G ^ (n & 7)) * 8,
                at + (i * 256 + wave * 64) * 16);
  }
  __syncthreads();

  f32x4 acc[4][4] = {};
  for (int ks = 0; ks < 8; ++ks) {
    bfrag bfr[4];
#pragma unroll
    for (int nt = 0; nt < 4; ++nt) {
      int n = nt * 16 + lr;
      bfr[nt] = *(const bfrag*)(at + n * 512 + (((ks * 4 + g) ^ (n & 7)) << 4));
    }
#pragma unroll
    for (int i = 0; i < 4; ++i) {
      int m = (wave * 4 + i) * 16 + lr;
      bfrag afr = *(const bfrag*)(Wvb + (size_t)m * CH + ks * 32 + g * 8);
#pragma unroll
      for (int nt = 0; nt < 4; ++nt) acc[i][nt] = MFMA16(afr, bfr[nt], acc[i][nt]);
    }
  }
  const float gam = gamma[0];
#pragma unroll
  for (int i = 0; i < 4; ++i)
#pragma unroll
    for (int nt = 0; nt < 4; ++nt) {
      int n = n0 + nt * 16 + lr;
#pragma unroll
      for (int r = 0; r < 4; ++r) {
        int m = (wave * 4 + i) * 16 + 4 * g + r;
        size_t off = (size_t)(b * CH + m) * NPIX + n;
        out[off] = x[off] + gam * (acc[i][nt][r] + bv[m]);
      }
    }
}

extern "C" void kernel_launch(void* const* d_in, const int* in_sizes, int n_in,
                              void* d_out, int out_size, void* d_ws, size_t ws_size,
                              hipStream_t stream) {
  const float* x   = (const float*)d_in[0];
  const float* Wf  = (const float*)d_in[1];
  const float* bfb = (const float*)d_in[2];
  const float* Wg  = (const float*)d_in[3];
  const float* bgb = (const float*)d_in[4];
  const float* Wh  = (const float*)d_in[5];
  const float* bhb = (const float*)d_in[6];
  const float* Wv  = (const float*)d_in[7];
  const float* bv  = (const float*)d_in[8];
  const float* gam = (const float*)d_in[9];
  float* out = (float*)d_out;

  char* ws = (char*)d_ws;
  unsigned short* Wall = (unsigned short*)(ws);              // 160 KB
  unsigned short* Wvb  = (unsigned short*)(ws + 163840);     // 128 KB
  unsigned short* Q    = (unsigned short*)(ws + 294912);     // 2 MB
  unsigned short* K    = (unsigned short*)(ws + 2392064);    // 2 MB
  unsigned short* V    = (unsigned short*)(ws + 4489216);    // 16 MB (sigma-permuted Vp)
  unsigned short* attn = (unsigned short*)(ws + 21266432);   // 16 MB (end ~38 MB)

  prep_kernel<<<320, 256, 0, stream>>>(Wf, Wg, Wh, Wv, Wall, Wvb);
  proj_kernel<<<512, 256, 0, stream>>>(x, Wall, bfb, bgb, bhb, Q, K, V);
  attn_kernel<<<512, 256, 0, stream>>>(Q, K, V, attn);
  vproj_kernel<<<512, 256, 0, stream>>>(attn, Wvb, bv, x, gam, out);
}

// Round 7
// 178.764 us; speedup vs baseline: 1.1248x; 1.1248x over previous
//
#include <hip/hip_runtime.h>
#include <hip/hip_bf16.h>
#include <stdint.h>

// Problem constants
#define BATCH 8
#define CH    256     // C
#define CQK   32      // query/key channels
#define NPIX  4096    // H*W
#define MALL  320     // CQK + CQK + CH combined projection rows

using bfrag = __attribute__((ext_vector_type(8))) short;     // 8 bf16 = 4 VGPR (MFMA A/B)
using f32x4 = __attribute__((ext_vector_type(4))) float;     // MFMA C/D
using u32x2 = __attribute__((ext_vector_type(2))) unsigned int;

#define MFMA16(A, B, C) __builtin_amdgcn_mfma_f32_16x16x32_bf16(A, B, C, 0, 0, 0)

#if __has_builtin(__builtin_amdgcn_exp2f)
#define EXP2(x) __builtin_amdgcn_exp2f(x)
#else
#define EXP2(x) exp2f(x)
#endif

__device__ __forceinline__ unsigned short f2bf(float f) {
  union { float f; unsigned int u; } v; v.f = f;
  unsigned int r = v.u + 0x7FFFu + ((v.u >> 16) & 1u);   // RNE
  return (unsigned short)(r >> 16);
}

__device__ __forceinline__ void gload_lds16(const void* g, void* l) {
  __builtin_amdgcn_global_load_lds(
      (const __attribute__((address_space(1))) unsigned int*)g,
      (__attribute__((address_space(3))) unsigned int*)l, 16, 0, 0);
}

// ---------------- kernel 0: cast weights to bf16 ----------------
__global__ void prep_kernel(const float* __restrict__ Wf, const float* __restrict__ Wg,
                            const float* __restrict__ Wh, const float* __restrict__ Wv,
                            unsigned short* __restrict__ Wall, unsigned short* __restrict__ Wvb) {
  int i = blockIdx.x * 256 + threadIdx.x;
  if (i < MALL * CH) {
    int m = i >> 8, c = i & 255;
    float v = (m < CQK)     ? Wf[m * CH + c]
            : (m < 2 * CQK) ? Wg[(m - CQK) * CH + c]
                            : Wh[(m - 2 * CQK) * CH + c];
    Wall[i] = f2bf(v);
  }
  if (i < CH * CH) Wvb[i] = f2bf(Wv[i]);
}

// ---------------- kernel 1: f,g,h projections (MFMA GEMM) ----------------
// out[m][n] = sum_c Wall[m][c] * x[b][c][n]  for one 64-pixel tile; M=320, K=256.
// Q is pre-scaled by log2(e). V is written FRAGMENT-MAJOR:
//   Vp[((b*64 + n/64)*256 + c)*64 + (n%64)]
__global__ __launch_bounds__(256, 2)
void proj_kernel(const float* __restrict__ x, const unsigned short* __restrict__ Wall,
                 const float* __restrict__ bfb, const float* __restrict__ bgb,
                 const float* __restrict__ bhb,
                 unsigned short* __restrict__ Qo, unsigned short* __restrict__ Ko,
                 unsigned short* __restrict__ Vp) {
  __shared__ char xT[64 * 512];  // xT[n][c] bf16, rows 512B, 16B-chunk XOR (n&7)
  const int b  = blockIdx.x & 7;
  const int n0 = (blockIdx.x >> 3) * 64;
  const int tid = threadIdx.x;
  const int lane = tid & 63, wave = tid >> 6;
  const int lr = lane & 15, g = lane >> 4;

  // load + transpose x tile (fp32 -> bf16)
  for (int it = 0; it < 16; ++it) {
    int c = it * 16 + wave * 4 + g;
    int nn = lr * 4;
    const float4 v = *(const float4*)(x + (size_t)(b * CH + c) * NPIX + n0 + nn);
    const float* vp = (const float*)&v;
#pragma unroll
    for (int j = 0; j < 4; ++j) {
      int n = nn + j;
      int byteoff = n * 512 + (((c >> 3) ^ (n & 7)) << 4) + ((c & 7) * 2);
      *(unsigned short*)(xT + byteoff) = f2bf(vp[j]);
    }
  }
  __syncthreads();

  f32x4 acc[5][4] = {};
  for (int ks = 0; ks < 8; ++ks) {
    bfrag bfr[4];
#pragma unroll
    for (int nt = 0; nt < 4; ++nt) {
      int n = nt * 16 + lr;
      bfr[nt] = *(const bfrag*)(xT + n * 512 + (((ks * 4 + g) ^ (n & 7)) << 4));
    }
#pragma unroll
    for (int i = 0; i < 5; ++i) {
      int m = (wave + 4 * i) * 16 + lr;
      bfrag afr = *(const bfrag*)(Wall + (size_t)m * CH + ks * 32 + g * 8);
#pragma unroll
      for (int nt = 0; nt < 4; ++nt) acc[i][nt] = MFMA16(afr, bfr[nt], acc[i][nt]);
    }
  }

  const float L2E = 1.4426950408889634f;
  const int vtile = (b * 64 + (n0 >> 6)) * 256;   // fragment-major V tile base
#pragma unroll
  for (int i = 0; i < 5; ++i) {
    const int mt = wave + 4 * i;
#pragma unroll
    for (int nt = 0; nt < 4; ++nt) {
      const int nl = nt * 16 + lr;        // n within tile
      const int n  = n0 + nl;
      if (mt < 2) {                     // f -> Q (scaled by log2 e)
        float v0 = (acc[i][nt][0] + bfb[mt * 16 + 4 * g + 0]) * L2E;
        float v1 = (acc[i][nt][1] + bfb[mt * 16 + 4 * g + 1]) * L2E;
        float v2 = (acc[i][nt][2] + bfb[mt * 16 + 4 * g + 2]) * L2E;
        float v3 = (acc[i][nt][3] + bfb[mt * 16 + 4 * g + 3]) * L2E;
        u32x2 pk;
        pk[0] = (unsigned)f2bf(v0) | ((unsigned)f2bf(v1) << 16);
        pk[1] = (unsigned)f2bf(v2) | ((unsigned)f2bf(v3) << 16);
        *(u32x2*)(Qo + (size_t)(b * NPIX + n) * CQK + mt * 16 + 4 * g) = pk;
      } else if (mt < 4) {              // g -> K
        int k0 = (mt - 2) * 16 + 4 * g;
        float v0 = acc[i][nt][0] + bgb[k0 + 0];
        float v1 = acc[i][nt][1] + bgb[k0 + 1];
        float v2 = acc[i][nt][2] + bgb[k0 + 2];
        float v3 = acc[i][nt][3] + bgb[k0 + 3];
        u32x2 pk;
        pk[0] = (unsigned)f2bf(v0) | ((unsigned)f2bf(v1) << 16);
        pk[1] = (unsigned)f2bf(v2) | ((unsigned)f2bf(v3) << 16);
        *(u32x2*)(Ko + (size_t)(b * NPIX + n) * CQK + k0) = pk;
      } else {                          // h -> V fragment-major
#pragma unroll
        for (int r = 0; r < 4; ++r) {
          int c = mt * 16 + 4 * g + r - 64;
          Vp[(size_t)(vtile + c) * 64 + nl] = f2bf(acc[i][nt][r] + bhb[c]);
        }
      }
    }
  }
}

// ---------------- kernel 2: flash attention ----------------
// 512 blocks (batch=bid&7 XCD-pinned, 64-q tile), 4 waves.
// j-split S (each wave one 16-j slice), P exchange via parity LDS, c-split PV.
// K and V are DOUBLE-BUFFERED IN REGISTERS ACROSS ITERATIONS: tile t+1's
// coalesced global loads issue at the top of iteration t and are consumed a
// full iteration later (~1500 cyc cover vs ~500-800 cyc loaded-L2 latency).
// Barriers are raw s_barrier + lgkmcnt(0) only; vmcnt is NEVER drained, so
// the prefetch rides across both barriers. Reg budget ~195 total (incl. 64
// AGPR acc) stays inside the 256 tier -> same 2 waves/SIMD as any variant.
__global__ __launch_bounds__(256)
void attn_kernel(const unsigned short* __restrict__ Qg, const unsigned short* __restrict__ Kg,
                 const unsigned short* __restrict__ Vp, unsigned short* __restrict__ Og) {
  __shared__ char Pb[16384];                // two 8KB parity P buffers [64q][64j]

  const int bid = blockIdx.x;
  const int b  = bid & 7;                   // batch == XCD pin
  const int q0 = (bid >> 3) * 64;
  const int tid = threadIdx.x;
  const int lane = tid & 63, wave = tid >> 6;
  const int lr = lane & 15, g = lane >> 4;

  const unsigned short* Qbase = Qg + (size_t)(b * NPIX + q0) * CQK;
  const unsigned short* Kf    = Kg + (size_t)b * NPIX * CQK + (16 * wave + lr) * CQK + g * 8;
  const unsigned short* Vf    = Vp + ((size_t)b * 64 * CH + 64 * wave + lr) * 64 + g * 8;

  // persistent Q fragments (B-operand of S^T)
  bfrag qf[4];
#pragma unroll
  for (int nt = 0; nt < 4; ++nt)
    qf[nt] = *(const bfrag*)(Qbase + (nt * 16 + lr) * CQK + g * 8);

  f32x4 acc[4][4] = {};
  float lp[4] = {0.f, 0.f, 0.f, 0.f};
  const int pwG   = 2 * wave + (g >> 1);                          // P write chunk index
  const int pwBase = lr * 128 + ((pwG ^ (lr & 7)) << 4) + ((g & 1) << 3);
  const int prBase0 = lr * 128 + (((0 * 4 + g) ^ (lr & 7)) << 4); // pf read base, ks=0
  const int prBase1 = lr * 128 + (((1 * 4 + g) ^ (lr & 7)) << 4); // pf read base, ks=1

  // ---- prologue: tile-0 K and V fragments in registers
  bfrag kf = *(const bfrag*)(Kf);
  bfrag vc[2][4];
#pragma unroll
  for (int ks = 0; ks < 2; ++ks)
#pragma unroll
    for (int nt = 0; nt < 4; ++nt)
      vc[ks][nt] = *(const bfrag*)(Vf + (size_t)(nt * 16) * 64 + ks * 32);

#pragma unroll 2
  for (int tl = 0; tl < 64; ++tl) {
    const int tn = (tl + 1) & 63;
    // ---- prefetch tile t+1 (consumed NEXT iteration): coalesced global
    bfrag vn[2][4];
    const unsigned short* vtn = Vf + (size_t)tn * CH * 64;
#pragma unroll
    for (int ks = 0; ks < 2; ++ks)
#pragma unroll
      for (int nt = 0; nt < 4; ++nt)
        vn[ks][nt] = *(const bfrag*)(vtn + (nt * 16) * 64 + ks * 32);
    bfrag kn = *(const bfrag*)(Kf + (size_t)(tn * 64) * CQK);

    char* Pw = Pb + ((tl & 1) << 13);       // parity buffer for this tile

    // ---- S^T phase: wave's 16-j block x 64 q, exp2, pack, P write
#pragma unroll
    for (int nt = 0; nt < 4; ++nt) {
      f32x4 zero = {0.f, 0.f, 0.f, 0.f};
      f32x4 st = MFMA16(kf, qf[nt], zero);
      float p0 = EXP2(st[0]), p1 = EXP2(st[1]);
      float p2 = EXP2(st[2]), p3 = EXP2(st[3]);
      lp[nt] += (p0 + p1) + (p2 + p3);
      unsigned lo, hi;
      asm("v_cvt_pk_bf16_f32 %0, %1, %2" : "=v"(lo) : "v"(p0), "v"(p1));
      asm("v_cvt_pk_bf16_f32 %0, %1, %2" : "=v"(hi) : "v"(p2), "v"(p3));
      u32x2 pk; pk[0] = lo; pk[1] = hi;
      *(u32x2*)(Pw + nt * 2048 + pwBase) = pk;
    }

    asm volatile("s_waitcnt lgkmcnt(0)" ::: "memory");   // own P writes done
    __builtin_amdgcn_s_barrier();                        // all P writes visible
    __builtin_amdgcn_sched_barrier(0);

    // ---- PV phase: wave owns c-block [64*wave, 64*wave+64), V from regs
#pragma unroll
    for (int ks = 0; ks < 2; ++ks) {
      bfrag pf[4];
      const int prB = ks ? prBase1 : prBase0;
#pragma unroll
      for (int mt = 0; mt < 4; ++mt)
        pf[mt] = *(const bfrag*)(Pw + mt * 2048 + prB);
#pragma unroll
      for (int mt = 0; mt < 4; ++mt)
#pragma unroll
        for (int nt = 0; nt < 4; ++nt)
          acc[mt][nt] = MFMA16(pf[mt], vc[ks][nt], acc[mt][nt]);
    }

    asm volatile("s_waitcnt lgkmcnt(0)" ::: "memory");   // own P reads done
    __builtin_amdgcn_s_barrier();                        // safe to overwrite parity
    __builtin_amdgcn_sched_barrier(0);

    // ---- rotate double buffers (renamed away by unroll 2)
    kf = kn;
#pragma unroll
    for (int ks = 0; ks < 2; ++ks)
#pragma unroll
      for (int nt = 0; nt < 4; ++nt)
        vc[ks][nt] = vn[ks][nt];
  }

  // ---- epilogue: softmax denominators and normalized store
#pragma unroll
  for (int nt = 0; nt < 4; ++nt) {
    lp[nt] += __shfl_xor(lp[nt], 16);
    lp[nt] += __shfl_xor(lp[nt], 32);
  }
  float* lred = (float*)Pb;   // reuse P region
  if (lane < 16) {
#pragma unroll
    for (int nt = 0; nt < 4; ++nt) lred[wave * 64 + nt * 16 + lr] = lp[nt];
  }
  __syncthreads();
  float inv[4][4];
#pragma unroll
  for (int mt = 0; mt < 4; ++mt)
#pragma unroll
    for (int r = 0; r < 4; ++r) {
      int q = mt * 16 + 4 * g + r;
      float s = lred[q] + lred[64 + q] + lred[128 + q] + lred[192 + q];
      inv[mt][r] = 1.0f / s;
    }
#pragma unroll
  for (int mt = 0; mt < 4; ++mt)
#pragma unroll
    for (int nt = 0; nt < 4; ++nt) {
      int c = 64 * wave + nt * 16 + lr;
#pragma unroll
      for (int r = 0; r < 4; ++r) {
        int q = q0 + mt * 16 + 4 * g + r;
        Og[(size_t)(b * NPIX + q) * CH + c] = f2bf(acc[mt][nt][r] * inv[mt][r]);
      }
    }
}

// ---------------- kernel 3: v-projection + residual ----------------
// out[b][m][n] = x[b][m][n] + gamma * (sum_c Wv[m][c]*attH[b][n][c] + bv[m])
__global__ __launch_bounds__(256, 2)
void vproj_kernel(const unsigned short* __restrict__ attn, const unsigned short* __restrict__ Wvb,
                  const float* __restrict__ bv, const float* __restrict__ x,
                  const float* __restrict__ gamma, float* __restrict__ out) {
  __shared__ char at[64 * 512];   // attH tile [64 n][256 c] bf16, swizzled
  const int b  = blockIdx.x & 7;
  const int n0 = (blockIdx.x >> 3) * 64;
  const int tid = threadIdx.x;
  const int lane = tid & 63, wave = tid >> 6;
  const int lr = lane & 15, g = lane >> 4;

#pragma unroll
  for (int i = 0; i < 8; ++i) {
    int ch = i * 256 + tid;
    int n = ch >> 5, G = ch & 31;
    gload_lds16(attn + (size_t)(b * NPIX + n0 + n) * CH + (G ^ (n & 7)) * 8,
                at + (i * 256 + wave * 64) * 16);
  }
  __syncthreads();

  f32x4 acc[4][4] = {};
  for (int ks = 0; ks < 8; ++ks) {
    bfrag bfr[4];
#pragma unroll
    for (int nt = 0; nt < 4; ++nt) {
      int n = nt * 16 + lr;
      bfr[nt] = *(const bfrag*)(at + n * 512 + (((ks * 4 + g) ^ (n & 7)) << 4));
    }
#pragma unroll
    for (int i = 0; i < 4; ++i) {
      int m = (wave * 4 + i) * 16 + lr;
      bfrag afr = *(const bfrag*)(Wvb + (size_t)m * CH + ks * 32 + g * 8);
#pragma unroll
      for (int nt = 0; nt < 4; ++nt) acc[i][nt] = MFMA16(afr, bfr[nt], acc[i][nt]);
    }
  }
  const float gam = gamma[0];
#pragma unroll
  for (int i = 0; i < 4; ++i)
#pragma unroll
    for (int nt = 0; nt < 4; ++nt) {
      int n = n0 + nt * 16 + lr;
#pragma unroll
      for (int r = 0; r < 4; ++r) {
        int m = (wave * 4 + i) * 16 + 4 * g + r;
        size_t off = (size_t)(b * CH + m) * NPIX + n;
        out[off] = x[off] + gam * (acc[i][nt][r] + bv[m]);
      }
    }
}

extern "C" void kernel_launch(void* const* d_in, const int* in_sizes, int n_in,
                              void* d_out, int out_size, void* d_ws, size_t ws_size,
                              hipStream_t stream) {
  const float* x   = (const float*)d_in[0];
  const float* Wf  = (const float*)d_in[1];
  const float* bfb = (const float*)d_in[2];
  const float* Wg  = (const float*)d_in[3];
  const float* bgb = (const float*)d_in[4];
  const float* Wh  = (const float*)d_in[5];
  const float* bhb = (const float*)d_in[6];
  const float* Wv  = (const float*)d_in[7];
  const float* bv  = (const float*)d_in[8];
  const float* gam = (const float*)d_in[9];
  float* out = (float*)d_out;

  char* ws = (char*)d_ws;
  unsigned short* Wall = (unsigned short*)(ws);              // 160 KB
  unsigned short* Wvb  = (unsigned short*)(ws + 163840);     // 128 KB
  unsigned short* Q    = (unsigned short*)(ws + 294912);     // 2 MB
  unsigned short* K    = (unsigned short*)(ws + 2392064);    // 2 MB
  unsigned short* V    = (unsigned short*)(ws + 4489216);    // 16 MB (fragment-major Vp)
  unsigned short* attn = (unsigned short*)(ws + 21266432);   // 16 MB (end ~38 MB)

  prep_kernel<<<320, 256, 0, stream>>>(Wf, Wg, Wh, Wv, Wall, Wvb);
  proj_kernel<<<512, 256, 0, stream>>>(x, Wall, bfb, bgb, bhb, Q, K, V);
  attn_kernel<<<512, 256, 0, stream>>>(Q, K, V, attn);
  vproj_kernel<<<512, 256, 0, stream>>>(attn, Wvb, bv, x, gam, out);
}